// Round 1
// baseline (908.705 us; speedup 1.0000x reference)
//
#include <hip/hip_runtime.h>

#define HW 4096
#define NC 512

// ---------------- Kernel 1: B[i][j] = sum_c content[c][i] * style[c][j] ----
// fp32 tiled GEMM (no fp32 MFMA on CDNA4). 128x128 tile, BK=16, 256 thr, 8x8/thread.
__global__ __launch_bounds__(256) void gemmB_kernel(const float* __restrict__ Cm,
                                                    const float* __restrict__ Sm,
                                                    float* __restrict__ B) {
    __shared__ float As[16][128];
    __shared__ float Bs[16][128];
    const int bi = blockIdx.y * 128;
    const int bj = blockIdx.x * 128;
    const int tid = threadIdx.x;
    const int tx = tid & 15, ty = tid >> 4;
    float acc[8][8];
#pragma unroll
    for (int m = 0; m < 8; ++m)
#pragma unroll
        for (int n = 0; n < 8; ++n) acc[m][n] = 0.f;

    for (int k0 = 0; k0 < NC; k0 += 16) {
#pragma unroll
        for (int t = 0; t < 2; ++t) {
            int f4 = tid + t * 256;          // 0..511 float4 slots
            int r = f4 >> 5;                 // k row 0..15
            int c4 = (f4 & 31) << 2;         // col 0..124
            *(float4*)&As[r][c4] = *(const float4*)&Cm[(size_t)(k0 + r) * HW + bi + c4];
            *(float4*)&Bs[r][c4] = *(const float4*)&Sm[(size_t)(k0 + r) * HW + bj + c4];
        }
        __syncthreads();
#pragma unroll
        for (int k = 0; k < 16; ++k) {
            float a[8], b[8];
            *(float4*)&a[0] = *(float4*)&As[k][ty * 8];
            *(float4*)&a[4] = *(float4*)&As[k][ty * 8 + 4];
            *(float4*)&b[0] = *(float4*)&Bs[k][tx * 8];
            *(float4*)&b[4] = *(float4*)&Bs[k][tx * 8 + 4];
#pragma unroll
            for (int m = 0; m < 8; ++m)
#pragma unroll
                for (int n = 0; n < 8; ++n)
                    acc[m][n] = fmaf(a[m], b[n], acc[m][n]);
        }
        __syncthreads();
    }
#pragma unroll
    for (int m = 0; m < 8; ++m) {
        int row = bi + ty * 8 + m;
        float4 v0 = make_float4(acc[m][0], acc[m][1], acc[m][2], acc[m][3]);
        float4 v1 = make_float4(acc[m][4], acc[m][5], acc[m][6], acc[m][7]);
        *(float4*)&B[(size_t)row * HW + bj + tx * 8] = v0;
        *(float4*)&B[(size_t)row * HW + bj + tx * 8 + 4] = v1;
    }
}

// ---------------- Kernel 2: score[i][j] = sum_{d in 3x3} B[i+d, j+d] (masked);
// corr[i] = argmax_j (first max). One block per content position i.
__global__ __launch_bounds__(256) void score_argmax_kernel(const float* __restrict__ B,
                                                           int* __restrict__ corr) {
    const int i = blockIdx.x;
    const int y = i >> 6, x = i & 63;
    const int tid = threadIdx.x;
    float best = -1e30f;
    int bidx = 0;
    for (int j = tid; j < HW; j += 256) {
        const int yj = j >> 6, xj = j & 63;
        float s = 0.f;
#pragma unroll
        for (int dy = -1; dy <= 1; ++dy) {
#pragma unroll
            for (int dx = -1; dx <= 1; ++dx) {
                int yc = y + dy, xc = x + dx;
                int ys = yj + dy, xs = xj + dx;
                bool ok = ((unsigned)yc < 64u) & ((unsigned)xc < 64u) &
                          ((unsigned)ys < 64u) & ((unsigned)xs < 64u);
                if (ok) {
                    int d = dy * 64 + dx;
                    s += B[(size_t)(i + d) * HW + (j + d)];
                }
            }
        }
        if (s > best) { best = s; bidx = j; }   // j increasing -> keeps first max
    }
    __shared__ float sv[256];
    __shared__ int si[256];
    sv[tid] = best;
    si[tid] = bidx;
    __syncthreads();
    for (int off = 128; off > 0; off >>= 1) {
        if (tid < off) {
            float v2 = sv[tid + off];
            int i2 = si[tid + off];
            if (v2 > sv[tid] || (v2 == sv[tid] && i2 < si[tid])) {
                sv[tid] = v2;
                si[tid] = i2;
            }
        }
        __syncthreads();
    }
    if (tid == 0) corr[i] = si[0];
}

// ---------------- Kernel 3: scalars[0] = sum(mask)*512; scalars[1] = 0 -------
__global__ __launch_bounds__(256) void masksum_kernel(const float* __restrict__ mask,
                                                      float* __restrict__ scalars) {
    __shared__ float s[256];
    const int tid = threadIdx.x;
    float v = 0.f;
    for (int k = tid; k < HW; k += 256) v += mask[k];
    s[tid] = v;
    __syncthreads();
    for (int off = 128; off > 0; off >>= 1) {
        if (tid < off) s[tid] += s[tid + off];
        __syncthreads();
    }
    if (tid == 0) {
        scalars[0] = s[0] * 512.0f;
        scalars[1] = 0.f;
    }
}

// ---------------- Kernel 4: fi = input*mask ; fm = style[:,corr]*mask --------
__global__ __launch_bounds__(256) void prep_kernel(const float* __restrict__ input,
                                                   const float* __restrict__ style,
                                                   const float* __restrict__ mask,
                                                   const int* __restrict__ corr,
                                                   float* __restrict__ fi,
                                                   float* __restrict__ fm) {
    const int g = blockIdx.x * 256 + threadIdx.x;   // 0 .. 512*4096-1
    const int hw = g & 4095;
    const int c = g >> 12;
    const float mk = mask[hw];
    fi[g] = input[g] * mk;
    fm[g] = style[(c << 12) + corr[hw]] * mk;
}

// ---------------- Kernel 5: loss partial = sum (G_img - G_sty)^2 over tile ---
// 64x64 output tile per block, K=4096 staged in LDS (transposed), 4x4/thread.
__global__ __launch_bounds__(256) void gram_loss_kernel(const float* __restrict__ fi,
                                                        const float* __restrict__ fm,
                                                        const float* __restrict__ scalars,
                                                        float* __restrict__ loss_acc) {
    __shared__ float SAi[16][64], SBi[16][64], SAm[16][64], SBm[16][64];
    const int a0 = blockIdx.y * 64, b0 = blockIdx.x * 64;
    const int tid = threadIdx.x;
    const int tx = tid & 15, ty = tid >> 4;
    const int r = tid >> 2, k4 = (tid & 3) << 2;
    float ai[4][4], am[4][4];
#pragma unroll
    for (int m = 0; m < 4; ++m)
#pragma unroll
        for (int n = 0; n < 4; ++n) { ai[m][n] = 0.f; am[m][n] = 0.f; }

    for (int k0 = 0; k0 < HW; k0 += 16) {
        float4 via = *(const float4*)&fi[(size_t)(a0 + r) * HW + k0 + k4];
        float4 vib = *(const float4*)&fi[(size_t)(b0 + r) * HW + k0 + k4];
        float4 vma = *(const float4*)&fm[(size_t)(a0 + r) * HW + k0 + k4];
        float4 vmb = *(const float4*)&fm[(size_t)(b0 + r) * HW + k0 + k4];
        SAi[k4 + 0][r] = via.x; SAi[k4 + 1][r] = via.y; SAi[k4 + 2][r] = via.z; SAi[k4 + 3][r] = via.w;
        SBi[k4 + 0][r] = vib.x; SBi[k4 + 1][r] = vib.y; SBi[k4 + 2][r] = vib.z; SBi[k4 + 3][r] = vib.w;
        SAm[k4 + 0][r] = vma.x; SAm[k4 + 1][r] = vma.y; SAm[k4 + 2][r] = vma.z; SAm[k4 + 3][r] = vma.w;
        SBm[k4 + 0][r] = vmb.x; SBm[k4 + 1][r] = vmb.y; SBm[k4 + 2][r] = vmb.z; SBm[k4 + 3][r] = vmb.w;
        __syncthreads();
#pragma unroll
        for (int k = 0; k < 16; ++k) {
            float a_i[4], b_i[4], a_m[4], b_m[4];
            *(float4*)a_i = *(float4*)&SAi[k][ty * 4];
            *(float4*)b_i = *(float4*)&SBi[k][tx * 4];
            *(float4*)a_m = *(float4*)&SAm[k][ty * 4];
            *(float4*)b_m = *(float4*)&SBm[k][tx * 4];
#pragma unroll
            for (int m = 0; m < 4; ++m)
#pragma unroll
                for (int n = 0; n < 4; ++n) {
                    ai[m][n] = fmaf(a_i[m], b_i[n], ai[m][n]);
                    am[m][n] = fmaf(a_m[m], b_m[n], am[m][n]);
                }
        }
        __syncthreads();
    }
    const float inv = 1.0f / scalars[0];
    float lsum = 0.f;
#pragma unroll
    for (int m = 0; m < 4; ++m)
#pragma unroll
        for (int n = 0; n < 4; ++n) {
            float d = (ai[m][n] - am[m][n]) * inv;
            lsum = fmaf(d, d, lsum);
        }
    __shared__ float red[256];
    red[tid] = lsum;
    __syncthreads();
    for (int off = 128; off > 0; off >>= 1) {
        if (tid < off) red[tid] += red[tid + off];
        __syncthreads();
    }
    if (tid == 0) atomicAdd(loss_acc, red[0]);
}

// ---------------- Kernel 6: out = acc * 100 / 512^2 --------------------------
__global__ void finalize_kernel(const float* __restrict__ scalars,
                                float* __restrict__ out) {
    out[0] = scalars[1] * (100.0f / 262144.0f);
}

extern "C" void kernel_launch(void* const* d_in, const int* in_sizes, int n_in,
                              void* d_out, int out_size, void* d_ws, size_t ws_size,
                              hipStream_t stream) {
    (void)in_sizes; (void)n_in; (void)out_size; (void)ws_size;
    const float* input   = (const float*)d_in[0];
    const float* style   = (const float*)d_in[1];
    const float* content = (const float*)d_in[2];
    const float* mask    = (const float*)d_in[3];
    float* out = (float*)d_out;

    float* wsf = (float*)d_ws;
    float* B  = wsf;                          // 4096*4096 floats (64 MB)
    float* fi = wsf;                          // reuses B space (B dead by then)
    float* fm = wsf + (size_t)NC * HW;        // next 512*4096 floats
    int*   corr = (int*)(wsf + (size_t)HW * HW);
    float* scalars = (float*)(corr + HW);     // [0]=mask_sum, [1]=loss accum

    gemmB_kernel<<<dim3(32, 32), 256, 0, stream>>>(content, style, B);
    score_argmax_kernel<<<HW, 256, 0, stream>>>(B, corr);
    masksum_kernel<<<1, 256, 0, stream>>>(mask, scalars);
    prep_kernel<<<(NC * HW) / 256, 256, 0, stream>>>(input, style, mask, corr, fi, fm);
    gram_loss_kernel<<<dim3(8, 8), 256, 0, stream>>>(fi, fm, scalars, &scalars[1]);
    finalize_kernel<<<1, 1, 0, stream>>>(scalars, out);
}

// Round 4
// 240.533 us; speedup vs baseline: 3.7779x; 3.7779x over previous
//
#include <hip/hip_runtime.h>

#define HW 4096
#define NC 512

using f32x4  = __attribute__((ext_vector_type(4))) float;
using bf16x8 = __attribute__((ext_vector_type(8))) short;

__device__ __forceinline__ unsigned short f2bf(float x) {
    unsigned u = __float_as_uint(x);
    unsigned r = (u + 0x7FFF + ((u >> 16) & 1)) >> 16;   // RNE
    return (unsigned short)r;
}
__device__ __forceinline__ float bf2f(unsigned short v) {
    return __uint_as_float(((unsigned)v) << 16);
}

#define GLDS16(g, l) __builtin_amdgcn_global_load_lds( \
    (const __attribute__((address_space(1))) void*)(g), \
    (__attribute__((address_space(3))) void*)(l), 16, 0, 0)

// ---------- Kernel 0: transpose+convert  src[C][HW] f32 -> dst[HW][C] bf16 ----
__global__ __launch_bounds__(256) void transconv_kernel(const float* __restrict__ content,
                                                        const float* __restrict__ style,
                                                        unsigned short* __restrict__ cT,
                                                        unsigned short* __restrict__ sT) {
    const float* src = blockIdx.z ? style : content;
    unsigned short* dst = blockIdx.z ? sT : cT;
    __shared__ float tile[32][33];
    const int i0 = blockIdx.x * 32;   // hw
    const int c0 = blockIdx.y * 32;   // channel
    const int tx = threadIdx.x & 31, ty = threadIdx.x >> 5;   // ty 0..7
#pragma unroll
    for (int r = 0; r < 32; r += 8)
        tile[ty + r][tx] = src[(size_t)(c0 + ty + r) * HW + i0 + tx];
    __syncthreads();
#pragma unroll
    for (int r = 0; r < 32; r += 8)
        dst[(size_t)(i0 + ty + r) * NC + c0 + tx] = f2bf(tile[tx][ty + r]);
}

// ---------- Kernel 1: Bb[i][j] = sum_c cT[i][c]*sT[j][c]  (bf16 MFMA, bf16 out)
__global__ __launch_bounds__(256) void gemmB_mfma(const unsigned short* __restrict__ cT,
                                                  const unsigned short* __restrict__ sT,
                                                  unsigned short* __restrict__ Bb) {
    __shared__ unsigned short As[128 * 32];
    __shared__ unsigned short Bs[128 * 32];
    const int tid = threadIdx.x;
    const int wid = tid >> 6, lane = tid & 63;
    const int wr = wid >> 1, wc = wid & 1;
    const int bi = blockIdx.y * 128, bj = blockIdx.x * 128;
    f32x4 acc[4][4] = {};

    const int r0 = tid >> 2,         k80 = (tid & 3) << 3;
    const int r1 = (tid + 256) >> 2, k81 = ((tid + 256) & 3) << 3;
    unsigned short* dst0 = &As[0] + (size_t)(wid * 64) * 8;
    unsigned short* dst1 = &As[0] + (size_t)(256 + wid * 64) * 8;
    unsigned short* dstB0 = &Bs[0] + (size_t)(wid * 64) * 8;
    unsigned short* dstB1 = &Bs[0] + (size_t)(256 + wid * 64) * 8;

    for (int k0 = 0; k0 < NC; k0 += 32) {
        GLDS16(&cT[(size_t)(bi + r0) * NC + k0 + k80], dst0);
        GLDS16(&cT[(size_t)(bi + r1) * NC + k0 + k81], dst1);
        GLDS16(&sT[(size_t)(bj + r0) * NC + k0 + k80], dstB0);
        GLDS16(&sT[(size_t)(bj + r1) * NC + k0 + k81], dstB1);
        __syncthreads();
        bf16x8 a_frag[4], b_frag[4];
#pragma unroll
        for (int m = 0; m < 4; ++m)
            a_frag[m] = *(const bf16x8*)&As[(wr * 64 + m * 16 + (lane & 15)) * 32 + (lane >> 4) * 8];
#pragma unroll
        for (int n = 0; n < 4; ++n)
            b_frag[n] = *(const bf16x8*)&Bs[(wc * 64 + n * 16 + (lane & 15)) * 32 + (lane >> 4) * 8];
#pragma unroll
        for (int m = 0; m < 4; ++m)
#pragma unroll
            for (int n = 0; n < 4; ++n)
                acc[m][n] = __builtin_amdgcn_mfma_f32_16x16x32_bf16(a_frag[m], b_frag[n], acc[m][n], 0, 0, 0);
        __syncthreads();
    }
#pragma unroll
    for (int m = 0; m < 4; ++m)
#pragma unroll
        for (int n = 0; n < 4; ++n)
#pragma unroll
            for (int r = 0; r < 4; ++r) {
                int row = bi + wr * 64 + m * 16 + (lane >> 4) * 4 + r;
                int col = bj + wc * 64 + n * 16 + (lane & 15);
                Bb[(size_t)row * HW + col] = f2bf(acc[m][n][r]);
            }
}

// ---------- Kernel 2: 9-point diagonal stencil on Bb + argmax per row --------
__global__ __launch_bounds__(256) void score_argmax_kernel(const unsigned short* __restrict__ Bb,
                                                           int* __restrict__ corr) {
    const int i = blockIdx.x;
    const int y = i >> 6, x = i & 63;
    const int tid = threadIdx.x;
    float best = -1e30f;
    int bidx = 0;
    for (int j = tid; j < HW; j += 256) {
        const int yj = j >> 6, xj = j & 63;
        float s = 0.f;
#pragma unroll
        for (int dy = -1; dy <= 1; ++dy) {
#pragma unroll
            for (int dx = -1; dx <= 1; ++dx) {
                int yc = y + dy, xc = x + dx;
                int ys = yj + dy, xs = xj + dx;
                bool ok = ((unsigned)yc < 64u) & ((unsigned)xc < 64u) &
                          ((unsigned)ys < 64u) & ((unsigned)xs < 64u);
                if (ok) {
                    int d = dy * 64 + dx;
                    s += bf2f(Bb[(size_t)(i + d) * HW + (j + d)]);
                }
            }
        }
        if (s > best) { best = s; bidx = j; }   // j increasing -> first max kept
    }
    __shared__ float sv[256];
    __shared__ int si[256];
    sv[tid] = best; si[tid] = bidx;
    __syncthreads();
    for (int off = 128; off > 0; off >>= 1) {
        if (tid < off) {
            float v2 = sv[tid + off]; int i2 = si[tid + off];
            if (v2 > sv[tid] || (v2 == sv[tid] && i2 < si[tid])) { sv[tid] = v2; si[tid] = i2; }
        }
        __syncthreads();
    }
    if (tid == 0) corr[i] = si[0];
}

// ---------- Kernel 3: scalars[0] = sum(mask)*512; scalars[1] = 0 -------------
__global__ __launch_bounds__(256) void masksum_kernel(const float* __restrict__ mask,
                                                      float* __restrict__ scalars) {
    __shared__ float s[256];
    const int tid = threadIdx.x;
    float v = 0.f;
    for (int k = tid; k < HW; k += 256) v += mask[k];
    s[tid] = v;
    __syncthreads();
    for (int off = 128; off > 0; off >>= 1) {
        if (tid < off) s[tid] += s[tid + off];
        __syncthreads();
    }
    if (tid == 0) { scalars[0] = s[0] * 512.0f; scalars[1] = 0.f; }
}

// ---------- Kernel 4: fib = bf16(input*mask); fmb = bf16(style[:,corr]*mask) -
__global__ __launch_bounds__(256) void prep_kernel(const float* __restrict__ input,
                                                   const float* __restrict__ style,
                                                   const float* __restrict__ mask,
                                                   const int* __restrict__ corr,
                                                   unsigned short* __restrict__ fib,
                                                   unsigned short* __restrict__ fmb) {
    const int g4 = (blockIdx.x * 256 + threadIdx.x) * 4;   // 4 elems/thread
    const int hw = g4 & 4095;
    const int c = g4 >> 12;
    float4 in = *(const float4*)&input[g4];
    float4 mk = *(const float4*)&mask[hw];
    ushort4 vi, vm;
    vi.x = f2bf(in.x * mk.x); vi.y = f2bf(in.y * mk.y);
    vi.z = f2bf(in.z * mk.z); vi.w = f2bf(in.w * mk.w);
    const float* srow = &style[(size_t)c << 12];
    vm.x = f2bf(srow[corr[hw + 0]] * mk.x);
    vm.y = f2bf(srow[corr[hw + 1]] * mk.y);
    vm.z = f2bf(srow[corr[hw + 2]] * mk.z);
    vm.w = f2bf(srow[corr[hw + 3]] * mk.w);
    *(ushort4*)&fib[g4] = vi;
    *(ushort4*)&fmb[g4] = vm;
}

// ---------- Kernel 5: partial grams via MFMA, K-split 16 ---------------------
// grid (4,4,16): 128x128 tile of both 512x512 grams over K-chunk 256.
__global__ __launch_bounds__(256) void gram_mfma(const unsigned short* __restrict__ fib,
                                                 const unsigned short* __restrict__ fmb,
                                                 float* __restrict__ GiP,
                                                 float* __restrict__ GmP) {
    __shared__ unsigned short Ai[128 * 32], Bi[128 * 32], Am[128 * 32], Bm[128 * 32];
    const int tid = threadIdx.x;
    const int wid = tid >> 6, lane = tid & 63;
    const int wr = wid >> 1, wc = wid & 1;
    const int bi = blockIdx.y * 128, bj = blockIdx.x * 128;
    const int kz = blockIdx.z * 256;
    f32x4 acci[4][4] = {}, accm[4][4] = {};

    const int r0 = tid >> 2,         k80 = (tid & 3) << 3;
    const int r1 = (tid + 256) >> 2, k81 = ((tid + 256) & 3) << 3;
    const size_t off0 = (size_t)(wid * 64) * 8;
    const size_t off1 = (size_t)(256 + wid * 64) * 8;

    for (int k0 = 0; k0 < 256; k0 += 32) {
        const int ka = kz + k0;
        GLDS16(&fib[(size_t)(bi + r0) * HW + ka + k80], &Ai[off0]);
        GLDS16(&fib[(size_t)(bi + r1) * HW + ka + k81], &Ai[off1]);
        GLDS16(&fib[(size_t)(bj + r0) * HW + ka + k80], &Bi[off0]);
        GLDS16(&fib[(size_t)(bj + r1) * HW + ka + k81], &Bi[off1]);
        GLDS16(&fmb[(size_t)(bi + r0) * HW + ka + k80], &Am[off0]);
        GLDS16(&fmb[(size_t)(bi + r1) * HW + ka + k81], &Am[off1]);
        GLDS16(&fmb[(size_t)(bj + r0) * HW + ka + k80], &Bm[off0]);
        GLDS16(&fmb[(size_t)(bj + r1) * HW + ka + k81], &Bm[off1]);
        __syncthreads();
        bf16x8 ai[4], bi_f[4], am[4], bm[4];
#pragma unroll
        for (int m = 0; m < 4; ++m) {
            int base = (wr * 64 + m * 16 + (lane & 15)) * 32 + (lane >> 4) * 8;
            ai[m] = *(const bf16x8*)&Ai[base];
            am[m] = *(const bf16x8*)&Am[base];
        }
#pragma unroll
        for (int n = 0; n < 4; ++n) {
            int base = (wc * 64 + n * 16 + (lane & 15)) * 32 + (lane >> 4) * 8;
            bi_f[n] = *(const bf16x8*)&Bi[base];
            bm[n] = *(const bf16x8*)&Bm[base];
        }
#pragma unroll
        for (int m = 0; m < 4; ++m)
#pragma unroll
            for (int n = 0; n < 4; ++n) {
                acci[m][n] = __builtin_amdgcn_mfma_f32_16x16x32_bf16(ai[m], bi_f[n], acci[m][n], 0, 0, 0);
                accm[m][n] = __builtin_amdgcn_mfma_f32_16x16x32_bf16(am[m], bm[n], accm[m][n], 0, 0, 0);
            }
        __syncthreads();
    }
    float* gi = GiP + (size_t)blockIdx.z * 262144;
    float* gm = GmP + (size_t)blockIdx.z * 262144;
#pragma unroll
    for (int m = 0; m < 4; ++m)
#pragma unroll
        for (int n = 0; n < 4; ++n)
#pragma unroll
            for (int r = 0; r < 4; ++r) {
                int row = bi + wr * 64 + m * 16 + (lane >> 4) * 4 + r;
                int col = bj + wc * 64 + n * 16 + (lane & 15);
                gi[(size_t)row * 512 + col] = acci[m][n][r];
                gm[(size_t)row * 512 + col] = accm[m][n][r];
            }
}

// ---------- Kernel 6: loss = sum over entries of ((sum_z Gi - sum_z Gm)/msum)^2
__global__ __launch_bounds__(256) void loss_kernel(const float* __restrict__ GiP,
                                                   const float* __restrict__ GmP,
                                                   float* __restrict__ scalars) {
    const int tid = threadIdx.x;
    const float inv = 1.0f / scalars[0];
    float lsum = 0.f;
    const int base = blockIdx.x * 1024;
    for (int e = base + tid; e < base + 1024; e += 256) {
        float gi = 0.f, gm = 0.f;
#pragma unroll
        for (int z = 0; z < 16; ++z) {
            gi += GiP[(size_t)z * 262144 + e];
            gm += GmP[(size_t)z * 262144 + e];
        }
        float d = (gi - gm) * inv;
        lsum = fmaf(d, d, lsum);
    }
    __shared__ float red[256];
    red[tid] = lsum;
    __syncthreads();
    for (int off = 128; off > 0; off >>= 1) {
        if (tid < off) red[tid] += red[tid + off];
        __syncthreads();
    }
    if (tid == 0) atomicAdd(&scalars[1], red[0]);
}

// ---------- Kernel 7: out = acc * 100 / 512^2 --------------------------------
__global__ void finalize_kernel(const float* __restrict__ scalars,
                                float* __restrict__ out) {
    out[0] = scalars[1] * (100.0f / 262144.0f);
}

extern "C" void kernel_launch(void* const* d_in, const int* in_sizes, int n_in,
                              void* d_out, int out_size, void* d_ws, size_t ws_size,
                              hipStream_t stream) {
    (void)in_sizes; (void)n_in; (void)out_size; (void)ws_size;
    const float* input   = (const float*)d_in[0];
    const float* style   = (const float*)d_in[1];
    const float* content = (const float*)d_in[2];
    const float* mask    = (const float*)d_in[3];
    float* out = (float*)d_out;

    // ws layout (phase-overlapped, peak ~40 MB):
    //   phase A: Bb bf16 [0,32MB) ; cT bf16 [32,36MB) ; sT bf16 [36,40MB)
    //   phase B: GiP f32 [0,16MB) ; GmP f32 [16,32MB) ; fib [32,36MB) ; fmb [36,40MB)
    //   corr int [40MB, +16KB) ; scalars after
    char* base = (char*)d_ws;
    unsigned short* Bb = (unsigned short*)base;                          // 4096*4096 bf16
    unsigned short* cT = (unsigned short*)(base + (((size_t)32) << 20)); // 4096*512
    unsigned short* sT = cT + (size_t)HW * NC;
    float* GiP = (float*)base;                                           // 16 * 512*512
    float* GmP = GiP + (size_t)16 * 262144;
    unsigned short* fib = (unsigned short*)(base + (((size_t)32) << 20)); // 512*4096
    unsigned short* fmb = fib + (size_t)NC * HW;
    int* corr = (int*)(base + (((size_t)40) << 20));
    float* scalars = (float*)(corr + HW);

    transconv_kernel<<<dim3(128, 16, 2), 256, 0, stream>>>(content, style, cT, sT);
    masksum_kernel<<<1, 256, 0, stream>>>(mask, scalars);
    gemmB_mfma<<<dim3(32, 32), 256, 0, stream>>>(cT, sT, Bb);
    score_argmax_kernel<<<HW, 256, 0, stream>>>(Bb, corr);
    prep_kernel<<<(NC * HW / 4) / 256, 256, 0, stream>>>(input, style, mask, corr, fib, fmb);
    gram_mfma<<<dim3(4, 4, 16), 256, 0, stream>>>(fib, fmb, GiP, GmP);
    loss_kernel<<<256, 256, 0, stream>>>(GiP, GmP, scalars);
    finalize_kernel<<<1, 1, 0, stream>>>(scalars, out);
}

// Round 7
// 180.841 us; speedup vs baseline: 5.0249x; 1.3301x over previous
//
#include <hip/hip_runtime.h>

#define HW 4096
#define NC 512

using f32x4  = __attribute__((ext_vector_type(4))) float;
using bf16x8 = __attribute__((ext_vector_type(8))) short;
using u32x4  = __attribute__((ext_vector_type(4))) unsigned;

__device__ __forceinline__ unsigned short f2bf(float x) {
    unsigned u = __float_as_uint(x);
    unsigned r = (u + 0x7FFF + ((u >> 16) & 1)) >> 16;   // RNE
    return (unsigned short)r;
}
__device__ __forceinline__ float bf2f(unsigned short v) {
    return __uint_as_float(((unsigned)v) << 16);
}

#define GLDS16(g, l) __builtin_amdgcn_global_load_lds( \
    (const __attribute__((address_space(1))) void*)(g), \
    (__attribute__((address_space(3))) void*)(l), 16, 0, 0)

// ---------- Kernel 0: transpose+convert  src[C][HW] f32 -> dst[HW][C] bf16 ----
__global__ __launch_bounds__(256) void transconv_kernel(const float* __restrict__ content,
                                                        const float* __restrict__ style,
                                                        unsigned short* __restrict__ cT,
                                                        unsigned short* __restrict__ sT) {
    const float* src = blockIdx.z ? style : content;
    unsigned short* dst = blockIdx.z ? sT : cT;
    __shared__ float tile[32][33];
    const int i0 = blockIdx.x * 32;   // hw
    const int c0 = blockIdx.y * 32;   // channel
    const int tx = threadIdx.x & 31, ty = threadIdx.x >> 5;   // ty 0..7
#pragma unroll
    for (int r = 0; r < 32; r += 8)
        tile[ty + r][tx] = src[(size_t)(c0 + ty + r) * HW + i0 + tx];
    __syncthreads();
#pragma unroll
    for (int r = 0; r < 32; r += 8)
        dst[(size_t)(i0 + ty + r) * NC + c0 + tx] = f2bf(tile[tx][ty + r]);
}

// ---------- Kernel 1: Bb[i][j] = sum_c cT[i][c]*sT[j][c]  (bf16 MFMA, bf16 out)
__global__ __launch_bounds__(256) void gemmB_mfma(const unsigned short* __restrict__ cT,
                                                  const unsigned short* __restrict__ sT,
                                                  unsigned short* __restrict__ Bb) {
    __shared__ unsigned short As[128 * 32];
    __shared__ unsigned short Bs[128 * 32];
    const int tid = threadIdx.x;
    const int wid = tid >> 6, lane = tid & 63;
    const int wr = wid >> 1, wc = wid & 1;
    const int bi = blockIdx.y * 128, bj = blockIdx.x * 128;
    f32x4 acc[4][4] = {};

    const int r0 = tid >> 2,         k80 = (tid & 3) << 3;
    const int r1 = (tid + 256) >> 2, k81 = ((tid + 256) & 3) << 3;
    unsigned short* dst0 = &As[0] + (size_t)(wid * 64) * 8;
    unsigned short* dst1 = &As[0] + (size_t)(256 + wid * 64) * 8;
    unsigned short* dstB0 = &Bs[0] + (size_t)(wid * 64) * 8;
    unsigned short* dstB1 = &Bs[0] + (size_t)(256 + wid * 64) * 8;

    for (int k0 = 0; k0 < NC; k0 += 32) {
        GLDS16(&cT[(size_t)(bi + r0) * NC + k0 + k80], dst0);
        GLDS16(&cT[(size_t)(bi + r1) * NC + k0 + k81], dst1);
        GLDS16(&sT[(size_t)(bj + r0) * NC + k0 + k80], dstB0);
        GLDS16(&sT[(size_t)(bj + r1) * NC + k0 + k81], dstB1);
        __syncthreads();
        bf16x8 a_frag[4], b_frag[4];
#pragma unroll
        for (int m = 0; m < 4; ++m)
            a_frag[m] = *(const bf16x8*)&As[(wr * 64 + m * 16 + (lane & 15)) * 32 + (lane >> 4) * 8];
#pragma unroll
        for (int n = 0; n < 4; ++n)
            b_frag[n] = *(const bf16x8*)&Bs[(wc * 64 + n * 16 + (lane & 15)) * 32 + (lane >> 4) * 8];
#pragma unroll
        for (int m = 0; m < 4; ++m)
#pragma unroll
            for (int n = 0; n < 4; ++n)
                acc[m][n] = __builtin_amdgcn_mfma_f32_16x16x32_bf16(a_frag[m], b_frag[n], acc[m][n], 0, 0, 0);
        __syncthreads();
    }
#pragma unroll
    for (int m = 0; m < 4; ++m)
#pragma unroll
        for (int n = 0; n < 4; ++n)
#pragma unroll
            for (int r = 0; r < 4; ++r) {
                int row = bi + wr * 64 + m * 16 + (lane >> 4) * 4 + r;
                int col = bj + wc * 64 + n * 16 + (lane & 15);
                Bb[(size_t)row * HW + col] = f2bf(acc[m][n][r]);
            }
}

// ---------- Kernel 2a: Dx[r][j] = B[r][j] + mx-? B[r-1][j-1] + mx+? B[r+1][j+1]
// Separable x-pass of the 9-pt diagonal stencil. Thread owns 32 contiguous cols.
__global__ __launch_bounds__(256) void stencilx_kernel(const unsigned short* __restrict__ Bb,
                                                       unsigned short* __restrict__ Dx) {
    const int t = threadIdx.x;
    const int r = blockIdx.x * 2 + (t >> 7);
    const int base = (t & 127) * 32;
    const int xr = r & 63;
    const bool okm = xr > 0, okp = xr < 63;
    const bool typeB = (base & 63) != 0;   // base%64==32

    const unsigned short* rowM = Bb + (size_t)r * HW + base;
    const unsigned short* rowL = rowM - HW;
    const unsigned short* rowH = rowM + HW;

    const u32x4 Z = {0, 0, 0, 0};
    u32x4 mid[4], lov[4], hiv[4];
#pragma unroll
    for (int k = 0; k < 4; ++k) {
        mid[k] = *(const u32x4*)(rowM + 8 * k);
        lov[k] = okm ? *(const u32x4*)(rowL + 8 * k) : Z;
        hiv[k] = okp ? *(const u32x4*)(rowH + 8 * k) : Z;
    }
    // edge scalars: type A (base%64==0) never needs left (x_j=0 masked);
    // type B never needs right (x_j=63 masked). Zeros encode the mask.
    float eL = (typeB && okm) ? bf2f(rowL[-1]) : 0.f;
    float eR = (!typeB && okp) ? bf2f(rowH[32]) : 0.f;

    float fm_[32], fl[32], fh[32];
#pragma unroll
    for (int k = 0; k < 4; ++k)
#pragma unroll
        for (int d = 0; d < 4; ++d) {
            unsigned dm = mid[k][d], dl = lov[k][d], dh = hiv[k][d];
            int e = k * 8 + d * 2;
            fm_[e]     = __uint_as_float(dm << 16);
            fm_[e + 1] = __uint_as_float(dm & 0xFFFF0000u);
            fl[e]      = __uint_as_float(dl << 16);
            fl[e + 1]  = __uint_as_float(dl & 0xFFFF0000u);
            fh[e]      = __uint_as_float(dh << 16);
            fh[e + 1]  = __uint_as_float(dh & 0xFFFF0000u);
        }
    unsigned short outp[32];
#pragma unroll
    for (int e = 0; e < 32; ++e) {
        float lo_v = (e == 0) ? eL : fl[e - 1];
        float hi_v = (e == 31) ? eR : fh[e + 1];
        outp[e] = f2bf(fm_[e] + lo_v + hi_v);
    }
    unsigned short* o = Dx + (size_t)r * HW + base;
#pragma unroll
    for (int k = 0; k < 4; ++k)
        *(u32x4*)(o + 8 * k) = *(u32x4*)&outp[k * 8];
}

// ---------- Kernel 2b: score[i][j] = Dx[i][j] + my? Dx[i-64][j-64] + mp? Dx[i+64][j+64]
// + first-max argmax over j. All shifts are 8-aligned: no shuffles.
__global__ __launch_bounds__(256) void stencily_argmax_kernel(const unsigned short* __restrict__ Dx,
                                                              int* __restrict__ corr) {
    const int i = blockIdx.x;
    const int yi = i >> 6;
    const int t = threadIdx.x;
    const bool okm = yi > 0, okp = yi < 63;
    const u32x4 Z = {0, 0, 0, 0};
    float best = -1e30f;
    int bestj = 0;
#pragma unroll
    for (int cc = 0; cc < 2; ++cc) {
        const int c0 = t * 16 + cc * 8;
        const unsigned short* pm = Dx + (size_t)i * HW + c0;
        const bool my = okm && (c0 >= 64);
        const bool mp = okp && (c0 < 4032);
        u32x4 m_ = *(const u32x4*)pm;
        u32x4 l_ = my ? *(const u32x4*)(pm - (size_t)64 * HW - 64) : Z;
        u32x4 h_ = mp ? *(const u32x4*)(pm + (size_t)64 * HW + 64) : Z;
#pragma unroll
        for (int d = 0; d < 4; ++d) {
            float s0 = __uint_as_float(m_[d] << 16) + __uint_as_float(l_[d] << 16) +
                       __uint_as_float(h_[d] << 16);
            float s1 = __uint_as_float(m_[d] & 0xFFFF0000u) + __uint_as_float(l_[d] & 0xFFFF0000u) +
                       __uint_as_float(h_[d] & 0xFFFF0000u);
            int j0 = c0 + 2 * d;
            if (s0 > best) { best = s0; bestj = j0; }
            if (s1 > best) { best = s1; bestj = j0 + 1; }
        }
    }
    __shared__ float sv[256];
    __shared__ int si[256];
    sv[t] = best; si[t] = bestj;
    __syncthreads();
    for (int off = 128; off > 0; off >>= 1) {
        if (t < off) {
            float v2 = sv[t + off]; int i2 = si[t + off];
            if (v2 > sv[t] || (v2 == sv[t] && i2 < si[t])) { sv[t] = v2; si[t] = i2; }
        }
        __syncthreads();
    }
    if (t == 0) corr[i] = si[0];
}

// ---------- Kernel 3: scalars[0] = sum(mask)*512; scalars[1] = 0 -------------
__global__ __launch_bounds__(256) void masksum_kernel(const float* __restrict__ mask,
                                                      float* __restrict__ scalars) {
    __shared__ float s[256];
    const int tid = threadIdx.x;
    float v = 0.f;
    for (int k = tid; k < HW; k += 256) v += mask[k];
    s[tid] = v;
    __syncthreads();
    for (int off = 128; off > 0; off >>= 1) {
        if (tid < off) s[tid] += s[tid + off];
        __syncthreads();
    }
    if (tid == 0) { scalars[0] = s[0] * 512.0f; scalars[1] = 0.f; }
}

// ---------- Kernel 4: fib = bf16(input*mask); fmb = bf16(style[:,corr]*mask) -
__global__ __launch_bounds__(256) void prep_kernel(const float* __restrict__ input,
                                                   const float* __restrict__ style,
                                                   const float* __restrict__ mask,
                                                   const int* __restrict__ corr,
                                                   unsigned short* __restrict__ fib,
                                                   unsigned short* __restrict__ fmb) {
    const int g4 = (blockIdx.x * 256 + threadIdx.x) * 4;   // 4 elems/thread
    const int hw = g4 & 4095;
    const int c = g4 >> 12;
    float4 in = *(const float4*)&input[g4];
    float4 mk = *(const float4*)&mask[hw];
    ushort4 vi, vm;
    vi.x = f2bf(in.x * mk.x); vi.y = f2bf(in.y * mk.y);
    vi.z = f2bf(in.z * mk.z); vi.w = f2bf(in.w * mk.w);
    const float* srow = &style[(size_t)c << 12];
    vm.x = f2bf(srow[corr[hw + 0]] * mk.x);
    vm.y = f2bf(srow[corr[hw + 1]] * mk.y);
    vm.z = f2bf(srow[corr[hw + 2]] * mk.z);
    vm.w = f2bf(srow[corr[hw + 3]] * mk.w);
    *(ushort4*)&fib[g4] = vi;
    *(ushort4*)&fmb[g4] = vm;
}

// ---------- Kernel 5: partial grams via MFMA, K-split 16 ---------------------
// grid (4,4,16): 128x128 tile of both 512x512 grams over K-chunk 256.
__global__ __launch_bounds__(256) void gram_mfma(const unsigned short* __restrict__ fib,
                                                 const unsigned short* __restrict__ fmb,
                                                 float* __restrict__ GiP,
                                                 float* __restrict__ GmP) {
    __shared__ unsigned short Ai[128 * 32], Bi[128 * 32], Am[128 * 32], Bm[128 * 32];
    const int tid = threadIdx.x;
    const int wid = tid >> 6, lane = tid & 63;
    const int wr = wid >> 1, wc = wid & 1;
    const int bi = blockIdx.y * 128, bj = blockIdx.x * 128;
    const int kz = blockIdx.z * 256;
    f32x4 acci[4][4] = {}, accm[4][4] = {};

    const int r0 = tid >> 2,         k80 = (tid & 3) << 3;
    const int r1 = (tid + 256) >> 2, k81 = ((tid + 256) & 3) << 3;
    const size_t off0 = (size_t)(wid * 64) * 8;
    const size_t off1 = (size_t)(256 + wid * 64) * 8;

    for (int k0 = 0; k0 < 256; k0 += 32) {
        const int ka = kz + k0;
        GLDS16(&fib[(size_t)(bi + r0) * HW + ka + k80], &Ai[off0]);
        GLDS16(&fib[(size_t)(bi + r1) * HW + ka + k81], &Ai[off1]);
        GLDS16(&fib[(size_t)(bj + r0) * HW + ka + k80], &Bi[off0]);
        GLDS16(&fib[(size_t)(bj + r1) * HW + ka + k81], &Bi[off1]);
        GLDS16(&fmb[(size_t)(bi + r0) * HW + ka + k80], &Am[off0]);
        GLDS16(&fmb[(size_t)(bi + r1) * HW + ka + k81], &Am[off1]);
        GLDS16(&fmb[(size_t)(bj + r0) * HW + ka + k80], &Bm[off0]);
        GLDS16(&fmb[(size_t)(bj + r1) * HW + ka + k81], &Bm[off1]);
        __syncthreads();
        bf16x8 ai[4], bi_f[4], am[4], bm[4];
#pragma unroll
        for (int m = 0; m < 4; ++m) {
            int base = (wr * 64 + m * 16 + (lane & 15)) * 32 + (lane >> 4) * 8;
            ai[m] = *(const bf16x8*)&Ai[base];
            am[m] = *(const bf16x8*)&Am[base];
        }
#pragma unroll
        for (int n = 0; n < 4; ++n) {
            int base = (wc * 64 + n * 16 + (lane & 15)) * 32 + (lane >> 4) * 8;
            bi_f[n] = *(const bf16x8*)&Bi[base];
            bm[n] = *(const bf16x8*)&Bm[base];
        }
#pragma unroll
        for (int m = 0; m < 4; ++m)
#pragma unroll
            for (int n = 0; n < 4; ++n) {
                acci[m][n] = __builtin_amdgcn_mfma_f32_16x16x32_bf16(ai[m], bi_f[n], acci[m][n], 0, 0, 0);
                accm[m][n] = __builtin_amdgcn_mfma_f32_16x16x32_bf16(am[m], bm[n], accm[m][n], 0, 0, 0);
            }
        __syncthreads();
    }
    float* gi = GiP + (size_t)blockIdx.z * 262144;
    float* gm = GmP + (size_t)blockIdx.z * 262144;
#pragma unroll
    for (int m = 0; m < 4; ++m)
#pragma unroll
        for (int n = 0; n < 4; ++n)
#pragma unroll
            for (int r = 0; r < 4; ++r) {
                int row = bi + wr * 64 + m * 16 + (lane >> 4) * 4 + r;
                int col = bj + wc * 64 + n * 16 + (lane & 15);
                gi[(size_t)row * 512 + col] = acci[m][n][r];
                gm[(size_t)row * 512 + col] = accm[m][n][r];
            }
}

// ---------- Kernel 6: loss = sum over entries of ((sum_z Gi - sum_z Gm)/msum)^2
__global__ __launch_bounds__(256) void loss_kernel(const float* __restrict__ GiP,
                                                   const float* __restrict__ GmP,
                                                   float* __restrict__ scalars) {
    const int tid = threadIdx.x;
    const float inv = 1.0f / scalars[0];
    float lsum = 0.f;
    const int base = blockIdx.x * 1024;
    for (int e = base + tid; e < base + 1024; e += 256) {
        float gi = 0.f, gm = 0.f;
#pragma unroll
        for (int z = 0; z < 16; ++z) {
            gi += GiP[(size_t)z * 262144 + e];
            gm += GmP[(size_t)z * 262144 + e];
        }
        float d = (gi - gm) * inv;
        lsum = fmaf(d, d, lsum);
    }
    __shared__ float red[256];
    red[tid] = lsum;
    __syncthreads();
    for (int off = 128; off > 0; off >>= 1) {
        if (tid < off) red[tid] += red[tid + off];
        __syncthreads();
    }
    if (tid == 0) atomicAdd(&scalars[1], red[0]);
}

// ---------- Kernel 7: out = acc * 100 / 512^2 --------------------------------
__global__ void finalize_kernel(const float* __restrict__ scalars,
                                float* __restrict__ out) {
    out[0] = scalars[1] * (100.0f / 262144.0f);
}

extern "C" void kernel_launch(void* const* d_in, const int* in_sizes, int n_in,
                              void* d_out, int out_size, void* d_ws, size_t ws_size,
                              hipStream_t stream) {
    (void)in_sizes; (void)n_in; (void)out_size; (void)ws_size;
    const float* input   = (const float*)d_in[0];
    const float* style   = (const float*)d_in[1];
    const float* content = (const float*)d_in[2];
    const float* mask    = (const float*)d_in[3];
    float* out = (float*)d_out;

    // ws layout (phase-overlapped, peak ~64 MB; 67 MB proven safe in round 1):
    //   phase A: cT [32,36) sT [36,40)        -> gemmB writes Bb [0,32)
    //   phase B: stencilx writes Dx [32,64)   (cT/sT dead)
    //   phase C: prep writes fib [32,36) fmb [36,40)  (Dx dead after stencily)
    //            gram writes GiP [0,16) GmP [16,32)   (Bb dead after stencilx)
    //   corr at [64MB), scalars after.
    char* base = (char*)d_ws;
    unsigned short* Bb = (unsigned short*)base;                           // 4096*4096 bf16
    unsigned short* cT = (unsigned short*)(base + (((size_t)32) << 20));  // 4096*512
    unsigned short* sT = cT + (size_t)HW * NC;
    unsigned short* Dx = (unsigned short*)(base + (((size_t)32) << 20));  // 4096*4096 bf16
    float* GiP = (float*)base;                                            // 16 * 512*512
    float* GmP = GiP + (size_t)16 * 262144;
    unsigned short* fib = (unsigned short*)(base + (((size_t)32) << 20)); // 512*4096
    unsigned short* fmb = fib + (size_t)NC * HW;
    int* corr = (int*)(base + (((size_t)64) << 20));
    float* scalars = (float*)(corr + HW);

    transconv_kernel<<<dim3(128, 16, 2), 256, 0, stream>>>(content, style, cT, sT);
    masksum_kernel<<<1, 256, 0, stream>>>(mask, scalars);
    gemmB_mfma<<<dim3(32, 32), 256, 0, stream>>>(cT, sT, Bb);
    stencilx_kernel<<<2048, 256, 0, stream>>>(Bb, Dx);
    stencily_argmax_kernel<<<HW, 256, 0, stream>>>(Dx, corr);
    prep_kernel<<<(NC * HW / 4) / 256, 256, 0, stream>>>(input, style, mask, corr, fib, fmb);
    gram_mfma<<<dim3(4, 4, 16), 256, 0, stream>>>(fib, fmb, GiP, GmP);
    loss_kernel<<<256, 256, 0, stream>>>(GiP, GmP, scalars);
    finalize_kernel<<<1, 1, 0, stream>>>(scalars, out);
}

// Round 16
// 166.590 us; speedup vs baseline: 5.4547x; 1.0855x over previous
//
#include <hip/hip_runtime.h>

#define HW 4096
#define NC 512

using f32x4  = __attribute__((ext_vector_type(4))) float;
using bf16x8 = __attribute__((ext_vector_type(8))) short;
using u32x4  = __attribute__((ext_vector_type(4))) unsigned;

__device__ __forceinline__ unsigned short f2bf(float x) {
    unsigned u = __float_as_uint(x);
    unsigned r = (u + 0x7FFF + ((u >> 16) & 1)) >> 16;   // RNE
    return (unsigned short)r;
}
__device__ __forceinline__ float bf2f(unsigned short v) {
    return __uint_as_float(((unsigned)v) << 16);
}

#define GLDS16(g, l) __builtin_amdgcn_global_load_lds( \
    (const __attribute__((address_space(1))) void*)(g), \
    (__attribute__((address_space(3))) void*)(l), 16, 0, 0)

// ---------- Kernel 0: transpose+convert src[C][HW] f32 -> dst[HW][C] bf16,
// with masksum fused as grid slice z==2 (single active block).
__global__ __launch_bounds__(256) void transconv_kernel(const float* __restrict__ content,
                                                        const float* __restrict__ style,
                                                        unsigned short* __restrict__ cT,
                                                        unsigned short* __restrict__ sT,
                                                        const float* __restrict__ mask,
                                                        float* __restrict__ scalars) {
    if (blockIdx.z == 2) {
        if (blockIdx.x || blockIdx.y) return;
        __shared__ float s[256];
        const int tid = threadIdx.x;
        float v = 0.f;
        for (int k = tid; k < HW; k += 256) v += mask[k];
        s[tid] = v;
        __syncthreads();
        for (int off = 128; off > 0; off >>= 1) {
            if (tid < off) s[tid] += s[tid + off];
            __syncthreads();
        }
        if (tid == 0) {
            scalars[0] = s[0] * 512.0f;       // mask_sum * C
            scalars[1] = 0.f;                 // loss accumulator
            ((unsigned*)scalars)[2] = 0u;     // done-block counter
        }
        return;
    }
    const float* src = blockIdx.z ? style : content;
    unsigned short* dst = blockIdx.z ? sT : cT;
    __shared__ float tile[32][33];
    const int i0 = blockIdx.x * 32;   // hw
    const int c0 = blockIdx.y * 32;   // channel
    const int tx = threadIdx.x & 31, ty = threadIdx.x >> 5;   // ty 0..7
#pragma unroll
    for (int r = 0; r < 32; r += 8)
        tile[ty + r][tx] = src[(size_t)(c0 + ty + r) * HW + i0 + tx];
    __syncthreads();
#pragma unroll
    for (int r = 0; r < 32; r += 8)
        dst[(size_t)(i0 + ty + r) * NC + c0 + tx] = f2bf(tile[tx][ty + r]);
}

// ---------- Kernel 1: Bb[i][j] = sum_c cT[i][c]*sT[j][c]  (bf16 MFMA, bf16 out)
__global__ __launch_bounds__(256) void gemmB_mfma(const unsigned short* __restrict__ cT,
                                                  const unsigned short* __restrict__ sT,
                                                  unsigned short* __restrict__ Bb) {
    __shared__ unsigned short As[128 * 32];
    __shared__ unsigned short Bs[128 * 32];
    const int tid = threadIdx.x;
    const int wid = tid >> 6, lane = tid & 63;
    const int wr = wid >> 1, wc = wid & 1;
    const int bi = blockIdx.y * 128, bj = blockIdx.x * 128;
    f32x4 acc[4][4] = {};

    const int r0 = tid >> 2,         k80 = (tid & 3) << 3;
    const int r1 = (tid + 256) >> 2, k81 = ((tid + 256) & 3) << 3;
    unsigned short* dst0 = &As[0] + (size_t)(wid * 64) * 8;
    unsigned short* dst1 = &As[0] + (size_t)(256 + wid * 64) * 8;
    unsigned short* dstB0 = &Bs[0] + (size_t)(wid * 64) * 8;
    unsigned short* dstB1 = &Bs[0] + (size_t)(256 + wid * 64) * 8;

    for (int k0 = 0; k0 < NC; k0 += 32) {
        GLDS16(&cT[(size_t)(bi + r0) * NC + k0 + k80], dst0);
        GLDS16(&cT[(size_t)(bi + r1) * NC + k0 + k81], dst1);
        GLDS16(&sT[(size_t)(bj + r0) * NC + k0 + k80], dstB0);
        GLDS16(&sT[(size_t)(bj + r1) * NC + k0 + k81], dstB1);
        __syncthreads();
        bf16x8 a_frag[4], b_frag[4];
#pragma unroll
        for (int m = 0; m < 4; ++m)
            a_frag[m] = *(const bf16x8*)&As[(wr * 64 + m * 16 + (lane & 15)) * 32 + (lane >> 4) * 8];
#pragma unroll
        for (int n = 0; n < 4; ++n)
            b_frag[n] = *(const bf16x8*)&Bs[(wc * 64 + n * 16 + (lane & 15)) * 32 + (lane >> 4) * 8];
#pragma unroll
        for (int m = 0; m < 4; ++m)
#pragma unroll
            for (int n = 0; n < 4; ++n)
                acc[m][n] = __builtin_amdgcn_mfma_f32_16x16x32_bf16(a_frag[m], b_frag[n], acc[m][n], 0, 0, 0);
        __syncthreads();
    }
#pragma unroll
    for (int m = 0; m < 4; ++m)
#pragma unroll
        for (int n = 0; n < 4; ++n)
#pragma unroll
            for (int r = 0; r < 4; ++r) {
                int row = bi + wr * 64 + m * 16 + (lane >> 4) * 4 + r;
                int col = bj + wc * 64 + n * 16 + (lane & 15);
                Bb[(size_t)row * HW + col] = f2bf(acc[m][n][r]);
            }
}

// ---------- Kernel 2a: separable x-pass of the 9-pt diagonal stencil ---------
__global__ __launch_bounds__(256) void stencilx_kernel(const unsigned short* __restrict__ Bb,
                                                       unsigned short* __restrict__ Dx) {
    const int t = threadIdx.x;
    const int r = blockIdx.x * 2 + (t >> 7);
    const int base = (t & 127) * 32;
    const int xr = r & 63;
    const bool okm = xr > 0, okp = xr < 63;
    const bool typeB = (base & 63) != 0;   // base%64==32

    const unsigned short* rowM = Bb + (size_t)r * HW + base;
    const unsigned short* rowL = rowM - HW;
    const unsigned short* rowH = rowM + HW;

    const u32x4 Z = {0, 0, 0, 0};
    u32x4 mid[4], lov[4], hiv[4];
#pragma unroll
    for (int k = 0; k < 4; ++k) {
        mid[k] = *(const u32x4*)(rowM + 8 * k);
        lov[k] = okm ? *(const u32x4*)(rowL + 8 * k) : Z;
        hiv[k] = okp ? *(const u32x4*)(rowH + 8 * k) : Z;
    }
    float eL = (typeB && okm) ? bf2f(rowL[-1]) : 0.f;
    float eR = (!typeB && okp) ? bf2f(rowH[32]) : 0.f;

    float fm_[32], fl[32], fh[32];
#pragma unroll
    for (int k = 0; k < 4; ++k)
#pragma unroll
        for (int d = 0; d < 4; ++d) {
            unsigned dm = mid[k][d], dl = lov[k][d], dh = hiv[k][d];
            int e = k * 8 + d * 2;
            fm_[e]     = __uint_as_float(dm << 16);
            fm_[e + 1] = __uint_as_float(dm & 0xFFFF0000u);
            fl[e]      = __uint_as_float(dl << 16);
            fl[e + 1]  = __uint_as_float(dl & 0xFFFF0000u);
            fh[e]      = __uint_as_float(dh << 16);
            fh[e + 1]  = __uint_as_float(dh & 0xFFFF0000u);
        }
    unsigned short outp[32];
#pragma unroll
    for (int e = 0; e < 32; ++e) {
        float lo_v = (e == 0) ? eL : fl[e - 1];
        float hi_v = (e == 31) ? eR : fh[e + 1];
        outp[e] = f2bf(fm_[e] + lo_v + hi_v);
    }
    unsigned short* o = Dx + (size_t)r * HW + base;
#pragma unroll
    for (int k = 0; k < 4; ++k)
        *(u32x4*)(o + 8 * k) = *(u32x4*)&outp[k * 8];
}

// ---------- Kernel 2b: y-pass + first-max argmax over j ----------------------
__global__ __launch_bounds__(256) void stencily_argmax_kernel(const unsigned short* __restrict__ Dx,
                                                              int* __restrict__ corr) {
    const int i = blockIdx.x;
    const int yi = i >> 6;
    const int t = threadIdx.x;
    const bool okm = yi > 0, okp = yi < 63;
    const u32x4 Z = {0, 0, 0, 0};
    float best = -1e30f;
    int bestj = 0;
#pragma unroll
    for (int cc = 0; cc < 2; ++cc) {
        const int c0 = t * 16 + cc * 8;
        const unsigned short* pm = Dx + (size_t)i * HW + c0;
        const bool my = okm && (c0 >= 64);
        const bool mp = okp && (c0 < 4032);
        u32x4 m_ = *(const u32x4*)pm;
        u32x4 l_ = my ? *(const u32x4*)(pm - (size_t)64 * HW - 64) : Z;
        u32x4 h_ = mp ? *(const u32x4*)(pm + (size_t)64 * HW + 64) : Z;
#pragma unroll
        for (int d = 0; d < 4; ++d) {
            float s0 = __uint_as_float(m_[d] << 16) + __uint_as_float(l_[d] << 16) +
                       __uint_as_float(h_[d] << 16);
            float s1 = __uint_as_float(m_[d] & 0xFFFF0000u) + __uint_as_float(l_[d] & 0xFFFF0000u) +
                       __uint_as_float(h_[d] & 0xFFFF0000u);
            int j0 = c0 + 2 * d;
            if (s0 > best) { best = s0; bestj = j0; }
            if (s1 > best) { best = s1; bestj = j0 + 1; }
        }
    }
    __shared__ float sv[256];
    __shared__ int si[256];
    sv[t] = best; si[t] = bestj;
    __syncthreads();
    for (int off = 128; off > 0; off >>= 1) {
        if (t < off) {
            float v2 = sv[t + off]; int i2 = si[t + off];
            if (v2 > sv[t] || (v2 == sv[t] && i2 < si[t])) { sv[t] = v2; si[t] = i2; }
        }
        __syncthreads();
    }
    if (t == 0) corr[i] = si[0];
}

// ---------- Kernel 4: fib = bf16(input*mask); fmb = bf16(style[:,corr]*mask) -
__global__ __launch_bounds__(256) void prep_kernel(const float* __restrict__ input,
                                                   const float* __restrict__ style,
                                                   const float* __restrict__ mask,
                                                   const int* __restrict__ corr,
                                                   unsigned short* __restrict__ fib,
                                                   unsigned short* __restrict__ fmb) {
    const int g4 = (blockIdx.x * 256 + threadIdx.x) * 4;   // 4 elems/thread
    const int hw = g4 & 4095;
    const int c = g4 >> 12;
    float4 in = *(const float4*)&input[g4];
    float4 mk = *(const float4*)&mask[hw];
    ushort4 vi, vm;
    vi.x = f2bf(in.x * mk.x); vi.y = f2bf(in.y * mk.y);
    vi.z = f2bf(in.z * mk.z); vi.w = f2bf(in.w * mk.w);
    const float* srow = &style[(size_t)c << 12];
    vm.x = f2bf(srow[corr[hw + 0]] * mk.x);
    vm.y = f2bf(srow[corr[hw + 1]] * mk.y);
    vm.z = f2bf(srow[corr[hw + 2]] * mk.z);
    vm.w = f2bf(srow[corr[hw + 3]] * mk.w);
    *(ushort4*)&fib[g4] = vi;
    *(ushort4*)&fmb[g4] = vm;
}

// ---------- Kernel 5: gram-DIFF partials, upper-triangle 64x64 tiles ---------
// grid (36, 8): tile t -> (ti<=tj) 64x64 block of (Gi - Gm); z-chunk K=512.
// P[(z*36 + t)*4096 + a*64 + b] = sum_k (fib_a fib_b - fmb_a fmb_b).
__global__ __launch_bounds__(256) void gram_diff_mfma(const unsigned short* __restrict__ fib,
                                                      const unsigned short* __restrict__ fmb,
                                                      float* __restrict__ P) {
    __shared__ unsigned short Ai[64 * 32], Bi[64 * 32], Am[64 * 32], Bm[64 * 32];
    const int tid = threadIdx.x;
    const int wid = tid >> 6, lane = tid & 63;
    const int wr = wid >> 1, wc = wid & 1;
    int q = blockIdx.x, ti = 0;
    while (q >= 8 - ti) { q -= 8 - ti; ++ti; }
    const int tj = ti + q;
    const int row0 = ti * 64, col0 = tj * 64;
    const int kz = blockIdx.y * 512;
    f32x4 acci[2][2] = {}, accm[2][2] = {};

    const int srow = tid >> 2, skoff = (tid & 3) << 3;
    unsigned short* bA = &Ai[wid * 512];
    unsigned short* bB = &Bi[wid * 512];
    unsigned short* bC = &Am[wid * 512];
    unsigned short* bD = &Bm[wid * 512];

    for (int k0 = 0; k0 < 512; k0 += 32) {
        const int ka = kz + k0 + skoff;
        GLDS16(&fib[(size_t)(row0 + srow) * HW + ka], bA);
        GLDS16(&fib[(size_t)(col0 + srow) * HW + ka], bB);
        GLDS16(&fmb[(size_t)(row0 + srow) * HW + ka], bC);
        GLDS16(&fmb[(size_t)(col0 + srow) * HW + ka], bD);
        __syncthreads();
        bf16x8 ai[2], bi_[2], am[2], bm[2];
#pragma unroll
        for (int m = 0; m < 2; ++m) {
            int off = (wr * 32 + m * 16 + (lane & 15)) * 32 + (lane >> 4) * 8;
            ai[m] = *(const bf16x8*)&Ai[off];
            am[m] = *(const bf16x8*)&Am[off];
        }
#pragma unroll
        for (int n = 0; n < 2; ++n) {
            int off = (wc * 32 + n * 16 + (lane & 15)) * 32 + (lane >> 4) * 8;
            bi_[n] = *(const bf16x8*)&Bi[off];
            bm[n] = *(const bf16x8*)&Bm[off];
        }
#pragma unroll
        for (int m = 0; m < 2; ++m)
#pragma unroll
            for (int n = 0; n < 2; ++n) {
                acci[m][n] = __builtin_amdgcn_mfma_f32_16x16x32_bf16(ai[m], bi_[n], acci[m][n], 0, 0, 0);
                accm[m][n] = __builtin_amdgcn_mfma_f32_16x16x32_bf16(am[m], bm[n], accm[m][n], 0, 0, 0);
            }
        __syncthreads();
    }
    float* Pz = P + ((size_t)blockIdx.y * 36 + blockIdx.x) * 4096;
#pragma unroll
    for (int m = 0; m < 2; ++m)
#pragma unroll
        for (int n = 0; n < 2; ++n)
#pragma unroll
            for (int r = 0; r < 4; ++r) {
                int a_ = wr * 32 + m * 16 + (lane >> 4) * 4 + r;
                int b_ = wc * 32 + n * 16 + (lane & 15);
                Pz[a_ * 64 + b_] = acci[m][n][r] - accm[m][n][r];
            }
}

// ---------- Kernel 6: loss = sum w*(sum_z P / msum)^2, finalize fused --------
// 144 blocks x 1024 entries; tile t = blk>>2 is uniform per block.
__global__ __launch_bounds__(256) void loss_final_kernel(const float* __restrict__ P,
                                                         float* __restrict__ scalars,
                                                         float* __restrict__ out) {
    const int tid = threadIdx.x;
    const int t = blockIdx.x >> 2;
    int q = t, ti = 0;
    while (q >= 8 - ti) { q -= 8 - ti; ++ti; }
    const float w = (q == 0) ? 1.0f : 2.0f;   // diagonal tile self-duplicates off-diag
    const float inv = 1.0f / scalars[0];
    float lsum = 0.f;
    const int e0 = blockIdx.x * 1024;
#pragma unroll
    for (int k = 0; k < 4; ++k) {
        const int e = e0 + k * 256 + tid;
        float g = 0.f;
#pragma unroll
        for (int z = 0; z < 8; ++z) g += P[(size_t)z * 147456 + e];
        float d = g * inv;
        lsum = fmaf(w * d, d, lsum);
    }
    __shared__ float red[256];
    red[tid] = lsum;
    __syncthreads();
    for (int off = 128; off > 0; off >>= 1) {
        if (tid < off) red[tid] += red[tid + off];
        __syncthreads();
    }
    if (tid == 0) {
        atomicAdd(&scalars[1], red[0]);
        __threadfence();
        unsigned old = atomicAdd(&((unsigned*)scalars)[2], 1u);
        if (old == 143u) {
            __threadfence();
            out[0] = *(volatile float*)&scalars[1] * (100.0f / 262144.0f);
        }
    }
}

extern "C" void kernel_launch(void* const* d_in, const int* in_sizes, int n_in,
                              void* d_out, int out_size, void* d_ws, size_t ws_size,
                              hipStream_t stream) {
    (void)in_sizes; (void)n_in; (void)out_size; (void)ws_size;
    const float* input   = (const float*)d_in[0];
    const float* style   = (const float*)d_in[1];
    const float* content = (const float*)d_in[2];
    const float* mask    = (const float*)d_in[3];
    float* out = (float*)d_out;

    // ws layout (phase-overlapped, peak 64 MB + 16 KB):
    //   phase A: cT [32,36) sT [36,40) MB     -> gemmB writes Bb [0,32)
    //   phase B: stencilx writes Dx [32,64)   (cT/sT dead)
    //   phase C: prep writes fib [0,4) fmb [4,8)      (Bb dead)
    //            gram_diff writes P [8,13)            (36*8*4096 f32 = 4.7 MB)
    //   corr int at [64MB), scalars after.
    char* base = (char*)d_ws;
    unsigned short* Bb = (unsigned short*)base;
    unsigned short* cT = (unsigned short*)(base + (((size_t)32) << 20));
    unsigned short* sT = cT + (size_t)HW * NC;
    unsigned short* Dx = (unsigned short*)(base + (((size_t)32) << 20));
    unsigned short* fib = (unsigned short*)base;
    unsigned short* fmb = fib + (size_t)NC * HW;
    float* P = (float*)(base + (((size_t)8) << 20));
    int* corr = (int*)(base + (((size_t)64) << 20));
    float* scalars = (float*)(corr + HW);

    transconv_kernel<<<dim3(128, 16, 3), 256, 0, stream>>>(content, style, cT, sT, mask, scalars);
    gemmB_mfma<<<dim3(32, 32), 256, 0, stream>>>(cT, sT, Bb);
    stencilx_kernel<<<2048, 256, 0, stream>>>(Bb, Dx);
    stencily_argmax_kernel<<<HW, 256, 0, stream>>>(Dx, corr);
    prep_kernel<<<(NC * HW / 4) / 256, 256, 0, stream>>>(input, style, mask, corr, fib, fmb);
    gram_diff_mfma<<<dim3(36, 8), 256, 0, stream>>>(fib, fmb, P);
    loss_final_kernel<<<144, 256, 0, stream>>>(P, scalars, out);
}